// Round 12
// baseline (895.760 us; speedup 1.0000x reference)
//
#include <hip/hip_runtime.h>
#include <hip/hip_bf16.h>

#define N_NODES 100000
#define N_EDGES 1200000
#define G_GRAPHS 128
#define CAP 64      // max in-degree capacity (Poisson mean 12; max deg @1e-10 ~ 40)
#define AP 68       // A row stride (floats): 272B = 17*16B, keeps b128 aligned
#define SLICE_N 12500   // N_NODES / 8 XCDs

// ---------------- CSR build (by dst), XCD-sliced (R11: 72->57MB writes) ------
__global__ void scatter_k(const int* __restrict__ ei, int* __restrict__ cnt,
                          int* __restrict__ adj) {
    int slice = blockIdx.x & 7;
    int e = (blockIdx.x >> 3) * 256 + threadIdx.x;
    if (e >= N_EDGES) return;
    int s = ei[e];             // src
    int d = ei[N_EDGES + e];   // dst
    s = min(max(s, 0), N_NODES - 1);
    d = min(max(d, 0), N_NODES - 1);
    if (d / SLICE_N != slice) return;    // another XCD's dst range
    int pos = atomicAdd(&cnt[d], 1);
    if (pos < CAP) adj[d * CAP + pos] = s;
}

// pad each adjacency row to a multiple of 8 with sentinel N_NODES (zero h-row)
__global__ void pad_k(int* __restrict__ cnt, int* __restrict__ adj) {
    int n = blockIdx.x * 256 + threadIdx.x;
    if (n >= N_NODES) return;
    int c = min(cnt[n], CAP);
    int p = min((c + 7) & ~7, CAP);
    for (int i = c; i < p; ++i) adj[n * CAP + i] = N_NODES;
    cnt[n] = p;
}

// ---------------- embedding gather ----------------
__global__ void embed_k(const int* __restrict__ x, const float4* __restrict__ emb,
                        float4* __restrict__ h) {
    int t = blockIdx.x * 256 + threadIdx.x;
    if (t >= N_NODES * 16) return;
    int n = t >> 4, q = t & 15;
    h[n * 16 + q] = emb[x[n] * 16 + q];
}

__device__ __forceinline__ void f4add(float4& a, const float4 b) {
    a.x += b.x; a.y += b.y; a.z += b.z; a.w += b.w;
}

// ---------------- neighbor aggregation + self term (gather, no atomics) -------
__global__ void agg_k(const float4* __restrict__ h, const int* __restrict__ adj,
                      const int* __restrict__ cnt, float4* __restrict__ agg) {
    int t = blockIdx.x * 256 + threadIdx.x;
    int n = t >> 4, q = t & 15;     // 16 lanes per node, float4 per lane
    if (n >= N_NODES) return;
    int deg = cnt[n];               // multiple of 8, <= CAP
    const int4* al4 = (const int4*)(adj + n * CAP);
    float4 a0 = h[n * 16 + q];      // self term fused
    float4 a1 = make_float4(0.f, 0.f, 0.f, 0.f);
    float4 a2 = a1, a3 = a1, a4 = a1, a5 = a1, a6 = a1, a7 = a1;
    int d8 = deg >> 3;
    for (int i = 0; i < d8; ++i) {
        int4 sa = al4[2 * i];
        int4 sb = al4[2 * i + 1];
        float4 v0 = h[sa.x * 16 + q];
        float4 v1 = h[sa.y * 16 + q];
        float4 v2 = h[sa.z * 16 + q];
        float4 v3 = h[sa.w * 16 + q];
        float4 v4 = h[sb.x * 16 + q];
        float4 v5 = h[sb.y * 16 + q];
        float4 v6 = h[sb.z * 16 + q];
        float4 v7 = h[sb.w * 16 + q];
        f4add(a0, v0); f4add(a1, v1); f4add(a2, v2); f4add(a3, v3);
        f4add(a4, v4); f4add(a5, v5); f4add(a6, v6); f4add(a7, v7);
    }
    f4add(a0, a1); f4add(a2, a3); f4add(a4, a5); f4add(a6, a7);
    f4add(a0, a2); f4add(a4, a6); f4add(a0, a4);
    agg[n * 16 + q] = a0;
}

__device__ __forceinline__ float elu(float v) { return v > 0.f ? v : expm1f(v); }

// 64x64x64 micro-tiled matmul, A row-major [node][k] stride AP.
// Per 4-k block: 4 broadcast A-fragments + 4 lane-consecutive W-fragments --
// zero bank conflicts (R11: transposed-A layout had 8-way on writes, 3.1M/dispatch).
__device__ __forceinline__ void mm64(const float* __restrict__ A,
                                     const float* __restrict__ Ws,
                                     float acc[4][4], int tr, int tc) {
    #pragma unroll
    for (int k4 = 0; k4 < 16; ++k4) {
        float4 av[4], wv[4];
        #pragma unroll
        for (int e = 0; e < 4; ++e)
            av[e] = *(const float4*)(A + (tr * 4 + e) * AP + k4 * 4);
        #pragma unroll
        for (int kk = 0; kk < 4; ++kk)
            wv[kk] = *(const float4*)(Ws + (k4 * 4 + kk) * 64 + tc * 4);
        #pragma unroll
        for (int e = 0; e < 4; ++e) {
            acc[e][0] += av[e].x * wv[0].x + av[e].y * wv[1].x + av[e].z * wv[2].x + av[e].w * wv[3].x;
            acc[e][1] += av[e].x * wv[0].y + av[e].y * wv[1].y + av[e].z * wv[2].y + av[e].w * wv[3].y;
            acc[e][2] += av[e].x * wv[0].z + av[e].y * wv[1].z + av[e].z * wv[2].z + av[e].w * wv[3].z;
            acc[e][3] += av[e].x * wv[0].w + av[e].y * wv[1].w + av[e].z * wv[2].w + av[e].w * wv[3].w;
        }
    }
}

// ---------------- fused MLP: h <- elu(W2^T(elu(BN(W1^T(agg)))) + b2) ----------
__global__ void __launch_bounds__(256) mlp_k(const float* __restrict__ agg,
    float* __restrict__ h,
    const float* __restrict__ W1, const float* __restrict__ b1,
    const float* __restrict__ g,  const float* __restrict__ be,
    const float* __restrict__ W2, const float* __restrict__ b2) {
    __shared__ float At[64 * AP];     // A row-major [node][k]; reused for y
    __shared__ float Ws1[4096];
    __shared__ float Ws2[4096];
    __shared__ float sc1[64], ep1[64], ep2[64];
    int tid = threadIdx.x;
    int n0 = blockIdx.x * 64;

    for (int idx = tid; idx < 1024; idx += 256) {
        ((float4*)Ws1)[idx] = ((const float4*)W1)[idx];
        ((float4*)Ws2)[idx] = ((const float4*)W2)[idx];
    }
    if (tid < 64) {
        const float inv = rsqrtf(1.0f + 1e-5f);
        float s = g[tid] * inv;
        sc1[tid] = s;
        ep1[tid] = b1[tid] * s + be[tid];
        ep2[tid] = b2[tid];
    }
    {   // stage A row-major: lane-consecutive b128 writes, conflict-free
        int r = tid >> 4, q = tid & 15;
        #pragma unroll
        for (int p = 0; p < 4; ++p) {
            int rr = p * 16 + r;
            int n = n0 + rr;
            float4 v = (n < N_NODES) ? ((const float4*)agg)[n * 16 + q]
                                     : make_float4(0.f, 0.f, 0.f, 0.f);
            *(float4*)(At + rr * AP + q * 4) = v;
        }
    }
    __syncthreads();

    int tr = tid >> 4, tc = tid & 15;
    float acc[4][4];
    #pragma unroll
    for (int e = 0; e < 4; ++e)
        #pragma unroll
        for (int j = 0; j < 4; ++j) acc[e][j] = 0.f;

    mm64(At, Ws1, acc, tr, tc);
    __syncthreads();                   // everyone done reading At
    #pragma unroll
    for (int e = 0; e < 4; ++e) {      // epilogue 1: BN affine + elu -> y[node][col]
        float4 o;
        o.x = elu(acc[e][0] * sc1[tc * 4 + 0] + ep1[tc * 4 + 0]);
        o.y = elu(acc[e][1] * sc1[tc * 4 + 1] + ep1[tc * 4 + 1]);
        o.z = elu(acc[e][2] * sc1[tc * 4 + 2] + ep1[tc * 4 + 2]);
        o.w = elu(acc[e][3] * sc1[tc * 4 + 3] + ep1[tc * 4 + 3]);
        *(float4*)(At + (tr * 4 + e) * AP + tc * 4) = o;   // lane-consecutive
    }
    __syncthreads();
    #pragma unroll
    for (int e = 0; e < 4; ++e)
        #pragma unroll
        for (int j = 0; j < 4; ++j) acc[e][j] = 0.f;

    mm64(At, Ws2, acc, tr, tc);
    #pragma unroll
    for (int e = 0; e < 4; ++e) {      // epilogue 2: +b2, outer elu, store
        int n = n0 + tr * 4 + e;
        if (n < N_NODES) {
            float4 o;
            o.x = elu(acc[e][0] + ep2[tc * 4 + 0]);
            o.y = elu(acc[e][1] + ep2[tc * 4 + 1]);
            o.z = elu(acc[e][2] + ep2[tc * 4 + 2]);
            o.w = elu(acc[e][3] + ep2[tc * 4 + 3]);
            ((float4*)h)[n * 16 + tc] = o;
        }
    }
}

// ---------------- mean pool per graph (batch sorted -> binary search bounds) ----
__global__ void pool_k(const float4* __restrict__ h, const int* __restrict__ batch,
                       float4* __restrict__ pooled) {
    int gph = blockIdx.x;
    int tid = threadIdx.x;          // 256
    int lo = 0, hi = N_NODES;
    while (lo < hi) { int mid = (lo + hi) >> 1; if (batch[mid] < gph) lo = mid + 1; else hi = mid; }
    int start = lo;
    hi = N_NODES;
    while (lo < hi) { int mid = (lo + hi) >> 1; if (batch[mid] < gph + 1) lo = mid + 1; else hi = mid; }
    int end = lo;
    int q = tid & 15, r = tid >> 4;
    float4 acc = make_float4(0.f, 0.f, 0.f, 0.f);
    for (int n = start + r; n < end; n += 16) {
        float4 v = h[n * 16 + q];
        acc.x += v.x; acc.y += v.y; acc.z += v.z; acc.w += v.w;
    }
    __shared__ float4 red[256];
    red[tid] = acc;
    __syncthreads();
    for (int s = 8; s > 0; s >>= 1) {
        if (r < s) {
            float4 o = red[(r + s) * 16 + q];
            float4 m = red[r * 16 + q];
            m.x += o.x; m.y += o.y; m.z += o.z; m.w += o.w;
            red[r * 16 + q] = m;
        }
        __syncthreads();
    }
    if (r == 0) {
        float invc = 1.0f / fmaxf((float)(end - start), 1.0f);
        float4 m = red[q];
        m.x *= invc; m.y *= invc; m.z *= invc; m.w *= invc;
        pooled[gph * 16 + q] = m;
    }
}

// ---------------- readout head: one wave per graph, lane j owns output j ------
__global__ void __launch_bounds__(256) head_k(const float* __restrict__ pooled,
    const float* __restrict__ Wr1, const float* __restrict__ br1,
    const float* __restrict__ Wr2, const float* __restrict__ br2,
    const float* __restrict__ Wo,  const float* __restrict__ bo,
    float* __restrict__ out) {
    __shared__ float ylds[4][64];
    int wid = threadIdx.x >> 6, j = threadIdx.x & 63;
    int gph = blockIdx.x * 4 + wid;   // 32 blocks x 4 waves = 128 graphs
    float acc = 0.f;
    #pragma unroll 8
    for (int k = 0; k < 64; ++k)
        acc += pooled[gph * 64 + k] * Wr1[k * 64 + j];   // bcast * coalesced
    float yv = acc + br1[j];
    ylds[wid][j] = elu(yv);
    __syncthreads();
    float acc2 = 0.f;
    #pragma unroll 8
    for (int k = 0; k < 64; ++k)
        acc2 += ylds[wid][k] * Wr2[k * 64 + j];
    float p = (acc2 + br2[j]) * Wo[j];
    #pragma unroll
    for (int off = 32; off > 0; off >>= 1) p += __shfl_down(p, off);
    if (j == 0) out[gph] = bo[0] + p;
}

extern "C" void kernel_launch(void* const* d_in, const int* in_sizes, int n_in,
                              void* d_out, int out_size, void* d_ws, size_t ws_size,
                              hipStream_t stream) {
    const int*   x     = (const int*)d_in[0];
    const int*   ei    = (const int*)d_in[1];
    const int*   batch = (const int*)d_in[2];
    const float* emb   = (const float*)d_in[3];
    const float* P[24];
    for (int i = 0; i < 24; ++i) P[i] = (const float*)d_in[4 + i];

    char* ws = (char*)d_ws;
    float* h      = (float*)(ws + 0);           // (N+1) rows x 256B
    float* agg    = (float*)(ws + 26000000);    // 25.6 MB
    int*   adj    = (int*)  (ws + 52000000);    // 25.6 MB (N*CAP)
    int*   cnt    = (int*)  (ws + 78000000);    // 0.4 MB
    float* pooled = (float*)(ws + 78400000);    // 32 KB

    hipMemsetAsync(cnt, 0, N_NODES * sizeof(int), stream);
    hipMemsetAsync(h + N_NODES * 64, 0, 64 * sizeof(float), stream);  // sentinel row
    scatter_k<<<8 * ((N_EDGES + 255) / 256), 256, 0, stream>>>(ei, cnt, adj);
    pad_k<<<(N_NODES + 255) / 256, 256, 0, stream>>>(cnt, adj);
    embed_k<<<(N_NODES * 16 + 255) / 256, 256, 0, stream>>>(x, (const float4*)emb, (float4*)h);
    for (int L = 0; L < 3; ++L) {
        const float* const* p = P + 6 * L;
        agg_k<<<(N_NODES * 16 + 255) / 256, 256, 0, stream>>>(
            (const float4*)h, adj, cnt, (float4*)agg);
        mlp_k<<<(N_NODES + 63) / 64, 256, 0, stream>>>(
            agg, h, p[0], p[1], p[2], p[3], p[4], p[5]);
    }
    pool_k<<<G_GRAPHS, 256, 0, stream>>>((const float4*)h, batch, (float4*)pooled);
    head_k<<<32, 256, 0, stream>>>(pooled, P[18], P[19], P[20], P[21], P[22], P[23],
                                   (float*)d_out);
}

// Round 13
// 463.276 us; speedup vs baseline: 1.9335x; 1.9335x over previous
//
#include <hip/hip_runtime.h>
#include <hip/hip_bf16.h>

#define N_NODES 100000
#define N_EDGES 1200000
#define G_GRAPHS 128
#define CAP 64      // max in-degree capacity (Poisson mean 12; max deg @1e-10 ~ 40)
#define AP 68       // A row stride (floats): 272B = 17*16B, keeps b128 aligned
#define SLICE_N 12500   // N_NODES / 8 XCDs

// ---------------- CSR build (by dst), XCD-sliced (R11: 72->57MB writes) ------
__global__ void scatter_k(const int* __restrict__ ei, int* __restrict__ cnt,
                          int* __restrict__ adj) {
    int slice = blockIdx.x & 7;
    int e = (blockIdx.x >> 3) * 256 + threadIdx.x;
    if (e >= N_EDGES) return;
    int s = ei[e];             // src
    int d = ei[N_EDGES + e];   // dst
    s = min(max(s, 0), N_NODES - 1);
    d = min(max(d, 0), N_NODES - 1);
    if (d / SLICE_N != slice) return;    // another XCD's dst range
    int pos = atomicAdd(&cnt[d], 1);
    if (pos < CAP) adj[d * CAP + pos] = s;
}

// pad each adjacency row to a multiple of 8 with sentinel N_NODES (zero h-row)
__global__ void pad_k(int* __restrict__ cnt, int* __restrict__ adj) {
    int n = blockIdx.x * 256 + threadIdx.x;
    if (n >= N_NODES) return;
    int c = min(cnt[n], CAP);
    int p = min((c + 7) & ~7, CAP);
    for (int i = c; i < p; ++i) adj[n * CAP + i] = N_NODES;
    cnt[n] = p;
}

// ---------------- embedding gather ----------------
__global__ void embed_k(const int* __restrict__ x, const float4* __restrict__ emb,
                        float4* __restrict__ h) {
    int t = blockIdx.x * 256 + threadIdx.x;
    if (t >= N_NODES * 16) return;
    int n = t >> 4, q = t & 15;
    h[n * 16 + q] = emb[x[n] * 16 + q];
}

__device__ __forceinline__ void f4add(float4& a, const float4 b) {
    a.x += b.x; a.y += b.y; a.z += b.z; a.w += b.w;
}

// ---------------- neighbor aggregation + self term (gather, no atomics) -------
__global__ void agg_k(const float4* __restrict__ h, const int* __restrict__ adj,
                      const int* __restrict__ cnt, float4* __restrict__ agg) {
    int t = blockIdx.x * 256 + threadIdx.x;
    int n = t >> 4, q = t & 15;     // 16 lanes per node, float4 per lane
    if (n >= N_NODES) return;
    int deg = cnt[n];               // multiple of 8, <= CAP
    const int4* al4 = (const int4*)(adj + n * CAP);
    float4 a0 = h[n * 16 + q];      // self term fused
    float4 a1 = make_float4(0.f, 0.f, 0.f, 0.f);
    float4 a2 = a1, a3 = a1, a4 = a1, a5 = a1, a6 = a1, a7 = a1;
    int d8 = deg >> 3;
    for (int i = 0; i < d8; ++i) {
        int4 sa = al4[2 * i];
        int4 sb = al4[2 * i + 1];
        float4 v0 = h[sa.x * 16 + q];
        float4 v1 = h[sa.y * 16 + q];
        float4 v2 = h[sa.z * 16 + q];
        float4 v3 = h[sa.w * 16 + q];
        float4 v4 = h[sb.x * 16 + q];
        float4 v5 = h[sb.y * 16 + q];
        float4 v6 = h[sb.z * 16 + q];
        float4 v7 = h[sb.w * 16 + q];
        f4add(a0, v0); f4add(a1, v1); f4add(a2, v2); f4add(a3, v3);
        f4add(a4, v4); f4add(a5, v5); f4add(a6, v6); f4add(a7, v7);
    }
    f4add(a0, a1); f4add(a2, a3); f4add(a4, a5); f4add(a6, a7);
    f4add(a0, a2); f4add(a4, a6); f4add(a0, a4);
    agg[n * 16 + q] = a0;
}

__device__ __forceinline__ float elu(float v) { return v > 0.f ? v : expm1f(v); }

// 64x64x64 micro-tiled matmul, A row-major [node][k] stride AP (conflict-free).
// R12 lesson: holding av[4]+wv[4] arrays across a fully-unrolled k4 loop let
// the scheduler hoist ~128 LDS loads -> 256 VGPR + spills. Here only ONE wv
// is live at a time (consumed with static component selects) and unroll is
// capped at 2, bounding the live set to ~45 VGPR.
#define FMA16(comp, wv)                                                        \
    acc[0][0] += av0.comp * wv.x; acc[0][1] += av0.comp * wv.y;                \
    acc[0][2] += av0.comp * wv.z; acc[0][3] += av0.comp * wv.w;                \
    acc[1][0] += av1.comp * wv.x; acc[1][1] += av1.comp * wv.y;                \
    acc[1][2] += av1.comp * wv.z; acc[1][3] += av1.comp * wv.w;                \
    acc[2][0] += av2.comp * wv.x; acc[2][1] += av2.comp * wv.y;                \
    acc[2][2] += av2.comp * wv.z; acc[2][3] += av2.comp * wv.w;                \
    acc[3][0] += av3.comp * wv.x; acc[3][1] += av3.comp * wv.y;                \
    acc[3][2] += av3.comp * wv.z; acc[3][3] += av3.comp * wv.w;

__device__ __forceinline__ void mm64(const float* __restrict__ A,
                                     const float* __restrict__ Ws,
                                     float acc[4][4], int tr, int tc) {
    #pragma unroll 2
    for (int k4 = 0; k4 < 16; ++k4) {
        float4 av0 = *(const float4*)(A + (tr * 4 + 0) * AP + k4 * 4);
        float4 av1 = *(const float4*)(A + (tr * 4 + 1) * AP + k4 * 4);
        float4 av2 = *(const float4*)(A + (tr * 4 + 2) * AP + k4 * 4);
        float4 av3 = *(const float4*)(A + (tr * 4 + 3) * AP + k4 * 4);
        {
            float4 wv = *(const float4*)(Ws + (k4 * 4 + 0) * 64 + tc * 4);
            FMA16(x, wv)
        }
        {
            float4 wv = *(const float4*)(Ws + (k4 * 4 + 1) * 64 + tc * 4);
            FMA16(y, wv)
        }
        {
            float4 wv = *(const float4*)(Ws + (k4 * 4 + 2) * 64 + tc * 4);
            FMA16(z, wv)
        }
        {
            float4 wv = *(const float4*)(Ws + (k4 * 4 + 3) * 64 + tc * 4);
            FMA16(w, wv)
        }
    }
}

// ---------------- fused MLP: h <- elu(W2^T(elu(BN(W1^T(agg)))) + b2) ----------
// __launch_bounds__(256,4): HARD 128-VGPR cap (R12: compiler chose 256 + spills)
__global__ void __launch_bounds__(256, 4) mlp_k(const float* __restrict__ agg,
    float* __restrict__ h,
    const float* __restrict__ W1, const float* __restrict__ b1,
    const float* __restrict__ g,  const float* __restrict__ be,
    const float* __restrict__ W2, const float* __restrict__ b2) {
    __shared__ float At[64 * AP];     // A row-major [node][k]; reused for y
    __shared__ float Ws1[4096];
    __shared__ float Ws2[4096];
    __shared__ float sc1[64], ep1[64], ep2[64];
    int tid = threadIdx.x;
    int n0 = blockIdx.x * 64;

    for (int idx = tid; idx < 1024; idx += 256) {
        ((float4*)Ws1)[idx] = ((const float4*)W1)[idx];
        ((float4*)Ws2)[idx] = ((const float4*)W2)[idx];
    }
    if (tid < 64) {
        const float inv = rsqrtf(1.0f + 1e-5f);
        float s = g[tid] * inv;
        sc1[tid] = s;
        ep1[tid] = b1[tid] * s + be[tid];
        ep2[tid] = b2[tid];
    }
    {   // stage A row-major: lane-consecutive b128 writes, conflict-free
        int r = tid >> 4, q = tid & 15;
        #pragma unroll
        for (int p = 0; p < 4; ++p) {
            int rr = p * 16 + r;
            int n = n0 + rr;
            float4 v = (n < N_NODES) ? ((const float4*)agg)[n * 16 + q]
                                     : make_float4(0.f, 0.f, 0.f, 0.f);
            *(float4*)(At + rr * AP + q * 4) = v;
        }
    }
    __syncthreads();

    int tr = tid >> 4, tc = tid & 15;
    float acc[4][4];
    #pragma unroll
    for (int e = 0; e < 4; ++e)
        #pragma unroll
        for (int j = 0; j < 4; ++j) acc[e][j] = 0.f;

    mm64(At, Ws1, acc, tr, tc);
    __syncthreads();                   // everyone done reading At
    #pragma unroll
    for (int e = 0; e < 4; ++e) {      // epilogue 1: BN affine + elu -> y[node][col]
        float4 o;
        o.x = elu(acc[e][0] * sc1[tc * 4 + 0] + ep1[tc * 4 + 0]);
        o.y = elu(acc[e][1] * sc1[tc * 4 + 1] + ep1[tc * 4 + 1]);
        o.z = elu(acc[e][2] * sc1[tc * 4 + 2] + ep1[tc * 4 + 2]);
        o.w = elu(acc[e][3] * sc1[tc * 4 + 3] + ep1[tc * 4 + 3]);
        *(float4*)(At + (tr * 4 + e) * AP + tc * 4) = o;   // lane-consecutive
    }
    __syncthreads();
    #pragma unroll
    for (int e = 0; e < 4; ++e)
        #pragma unroll
        for (int j = 0; j < 4; ++j) acc[e][j] = 0.f;

    mm64(At, Ws2, acc, tr, tc);
    #pragma unroll
    for (int e = 0; e < 4; ++e) {      // epilogue 2: +b2, outer elu, store
        int n = n0 + tr * 4 + e;
        if (n < N_NODES) {
            float4 o;
            o.x = elu(acc[e][0] + ep2[tc * 4 + 0]);
            o.y = elu(acc[e][1] + ep2[tc * 4 + 1]);
            o.z = elu(acc[e][2] + ep2[tc * 4 + 2]);
            o.w = elu(acc[e][3] + ep2[tc * 4 + 3]);
            ((float4*)h)[n * 16 + tc] = o;
        }
    }
}

// ---------------- mean pool per graph (batch sorted -> binary search bounds) ----
__global__ void pool_k(const float4* __restrict__ h, const int* __restrict__ batch,
                       float4* __restrict__ pooled) {
    int gph = blockIdx.x;
    int tid = threadIdx.x;          // 256
    int lo = 0, hi = N_NODES;
    while (lo < hi) { int mid = (lo + hi) >> 1; if (batch[mid] < gph) lo = mid + 1; else hi = mid; }
    int start = lo;
    hi = N_NODES;
    while (lo < hi) { int mid = (lo + hi) >> 1; if (batch[mid] < gph + 1) lo = mid + 1; else hi = mid; }
    int end = lo;
    int q = tid & 15, r = tid >> 4;
    float4 acc = make_float4(0.f, 0.f, 0.f, 0.f);
    for (int n = start + r; n < end; n += 16) {
        float4 v = h[n * 16 + q];
        acc.x += v.x; acc.y += v.y; acc.z += v.z; acc.w += v.w;
    }
    __shared__ float4 red[256];
    red[tid] = acc;
    __syncthreads();
    for (int s = 8; s > 0; s >>= 1) {
        if (r < s) {
            float4 o = red[(r + s) * 16 + q];
            float4 m = red[r * 16 + q];
            m.x += o.x; m.y += o.y; m.z += o.z; m.w += o.w;
            red[r * 16 + q] = m;
        }
        __syncthreads();
    }
    if (r == 0) {
        float invc = 1.0f / fmaxf((float)(end - start), 1.0f);
        float4 m = red[q];
        m.x *= invc; m.y *= invc; m.z *= invc; m.w *= invc;
        pooled[gph * 16 + q] = m;
    }
}

// ---------------- readout head: one wave per graph, lane j owns output j ------
__global__ void __launch_bounds__(256) head_k(const float* __restrict__ pooled,
    const float* __restrict__ Wr1, const float* __restrict__ br1,
    const float* __restrict__ Wr2, const float* __restrict__ br2,
    const float* __restrict__ Wo,  const float* __restrict__ bo,
    float* __restrict__ out) {
    __shared__ float ylds[4][64];
    int wid = threadIdx.x >> 6, j = threadIdx.x & 63;
    int gph = blockIdx.x * 4 + wid;   // 32 blocks x 4 waves = 128 graphs
    float acc = 0.f;
    #pragma unroll 8
    for (int k = 0; k < 64; ++k)
        acc += pooled[gph * 64 + k] * Wr1[k * 64 + j];   // bcast * coalesced
    float yv = acc + br1[j];
    ylds[wid][j] = elu(yv);
    __syncthreads();
    float acc2 = 0.f;
    #pragma unroll 8
    for (int k = 0; k < 64; ++k)
        acc2 += ylds[wid][k] * Wr2[k * 64 + j];
    float p = (acc2 + br2[j]) * Wo[j];
    #pragma unroll
    for (int off = 32; off > 0; off >>= 1) p += __shfl_down(p, off);
    if (j == 0) out[gph] = bo[0] + p;
}

extern "C" void kernel_launch(void* const* d_in, const int* in_sizes, int n_in,
                              void* d_out, int out_size, void* d_ws, size_t ws_size,
                              hipStream_t stream) {
    const int*   x     = (const int*)d_in[0];
    const int*   ei    = (const int*)d_in[1];
    const int*   batch = (const int*)d_in[2];
    const float* emb   = (const float*)d_in[3];
    const float* P[24];
    for (int i = 0; i < 24; ++i) P[i] = (const float*)d_in[4 + i];

    char* ws = (char*)d_ws;
    float* h      = (float*)(ws + 0);           // (N+1) rows x 256B
    float* agg    = (float*)(ws + 26000000);    // 25.6 MB
    int*   adj    = (int*)  (ws + 52000000);    // 25.6 MB (N*CAP)
    int*   cnt    = (int*)  (ws + 78000000);    // 0.4 MB
    float* pooled = (float*)(ws + 78400000);    // 32 KB

    hipMemsetAsync(cnt, 0, N_NODES * sizeof(int), stream);
    hipMemsetAsync(h + N_NODES * 64, 0, 64 * sizeof(float), stream);  // sentinel row
    scatter_k<<<8 * ((N_EDGES + 255) / 256), 256, 0, stream>>>(ei, cnt, adj);
    pad_k<<<(N_NODES + 255) / 256, 256, 0, stream>>>(cnt, adj);
    embed_k<<<(N_NODES * 16 + 255) / 256, 256, 0, stream>>>(x, (const float4*)emb, (float4*)h);
    for (int L = 0; L < 3; ++L) {
        const float* const* p = P + 6 * L;
        agg_k<<<(N_NODES * 16 + 255) / 256, 256, 0, stream>>>(
            (const float4*)h, adj, cnt, (float4*)agg);
        mlp_k<<<(N_NODES + 63) / 64, 256, 0, stream>>>(
            agg, h, p[0], p[1], p[2], p[3], p[4], p[5]);
    }
    pool_k<<<G_GRAPHS, 256, 0, stream>>>((const float4*)h, batch, (float4*)pooled);
    head_k<<<32, 256, 0, stream>>>(pooled, P[18], P[19], P[20], P[21], P[22], P[23],
                                   (float*)d_out);
}

// Round 14
// 419.235 us; speedup vs baseline: 2.1367x; 1.1051x over previous
//
#include <hip/hip_runtime.h>
#include <hip/hip_bf16.h>

#define N_NODES 100000
#define N_EDGES 1200000
#define G_GRAPHS 128
#define CAP 64      // max in-degree capacity (Poisson mean 12; max deg @1e-10 ~ 40)
#define AP 68       // A row stride (floats): 272B = 17*16B, keeps b128 aligned
#define SLICE_N 12500   // N_NODES / 8 XCDs

// ---------------- CSR build (by dst), XCD-sliced (R11: 72->57MB writes) ------
__global__ void scatter_k(const int* __restrict__ ei, int* __restrict__ cnt,
                          int* __restrict__ adj) {
    int slice = blockIdx.x & 7;
    int e = (blockIdx.x >> 3) * 256 + threadIdx.x;
    if (e >= N_EDGES) return;
    int s = ei[e];             // src
    int d = ei[N_EDGES + e];   // dst
    s = min(max(s, 0), N_NODES - 1);
    d = min(max(d, 0), N_NODES - 1);
    if (d / SLICE_N != slice) return;    // another XCD's dst range
    int pos = atomicAdd(&cnt[d], 1);
    if (pos < CAP) adj[d * CAP + pos] = s;
}

// ---------------- embedding gather ----------------
__global__ void embed_k(const int* __restrict__ x, const float4* __restrict__ emb,
                        float4* __restrict__ h) {
    int t = blockIdx.x * 256 + threadIdx.x;
    if (t >= N_NODES * 16) return;
    int n = t >> 4, q = t & 15;
    h[n * 16 + q] = emb[x[n] * 16 + q];
}

__device__ __forceinline__ void f4add(float4& a, const float4 b) {
    a.x += b.x; a.y += b.y; a.z += b.z; a.w += b.w;
}

__device__ __forceinline__ float elu(float v) { return v > 0.f ? v : expm1f(v); }

// 64x64x64 micro-tiled matmul, A row-major [node][k] stride AP (conflict-free).
// R12 lesson: one wv live at a time, unroll 2 -> ~45 VGPR live set.
#define FMA16(comp, wv)                                                        \
    acc[0][0] += av0.comp * wv.x; acc[0][1] += av0.comp * wv.y;                \
    acc[0][2] += av0.comp * wv.z; acc[0][3] += av0.comp * wv.w;                \
    acc[1][0] += av1.comp * wv.x; acc[1][1] += av1.comp * wv.y;                \
    acc[1][2] += av1.comp * wv.z; acc[1][3] += av1.comp * wv.w;                \
    acc[2][0] += av2.comp * wv.x; acc[2][1] += av2.comp * wv.y;                \
    acc[2][2] += av2.comp * wv.z; acc[2][3] += av2.comp * wv.w;                \
    acc[3][0] += av3.comp * wv.x; acc[3][1] += av3.comp * wv.y;                \
    acc[3][2] += av3.comp * wv.z; acc[3][3] += av3.comp * wv.w;

__device__ __forceinline__ void mm64(const float* __restrict__ A,
                                     const float* __restrict__ Ws,
                                     float acc[4][4], int tr, int tc) {
    #pragma unroll 2
    for (int k4 = 0; k4 < 16; ++k4) {
        float4 av0 = *(const float4*)(A + (tr * 4 + 0) * AP + k4 * 4);
        float4 av1 = *(const float4*)(A + (tr * 4 + 1) * AP + k4 * 4);
        float4 av2 = *(const float4*)(A + (tr * 4 + 2) * AP + k4 * 4);
        float4 av3 = *(const float4*)(A + (tr * 4 + 3) * AP + k4 * 4);
        {
            float4 wv = *(const float4*)(Ws + (k4 * 4 + 0) * 64 + tc * 4);
            FMA16(x, wv)
        }
        {
            float4 wv = *(const float4*)(Ws + (k4 * 4 + 1) * 64 + tc * 4);
            FMA16(y, wv)
        }
        {
            float4 wv = *(const float4*)(Ws + (k4 * 4 + 2) * 64 + tc * 4);
            FMA16(z, wv)
        }
        {
            float4 wv = *(const float4*)(Ws + (k4 * 4 + 3) * 64 + tc * 4);
            FMA16(w, wv)
        }
    }
}

// ------ fused GIN layer: hout <- elu(W2^T(elu(BN(W1^T(self+neigh)))) + b2) ----
// Gather fused into GEMM staging (kills the 51MB/layer agg round-trip + pad_k;
// masked tail selects sentinel row N_NODES instead of padded adjacency).
// Single shared W buffer: W2 staged after mm1's barrier -> 34.6KB LDS, 4 blk/CU.
__global__ void __launch_bounds__(256, 4) mlp_k(const float* __restrict__ hin,
    float* __restrict__ hout, const int* __restrict__ adj,
    const int* __restrict__ cnt,
    const float* __restrict__ W1, const float* __restrict__ b1,
    const float* __restrict__ g,  const float* __restrict__ be,
    const float* __restrict__ W2, const float* __restrict__ b2) {
    __shared__ float At[64 * AP];     // A row-major [node][k]; reused for y
    __shared__ float Wbuf[4096];      // W1 for mm1, then W2 for mm2
    __shared__ float sc1[64], ep1[64], ep2[64];
    int tid = threadIdx.x;
    int n0 = blockIdx.x * 64;
    const float4* h4 = (const float4*)hin;

    for (int idx = tid; idx < 1024; idx += 256)
        ((float4*)Wbuf)[idx] = ((const float4*)W1)[idx];
    if (tid < 64) {
        const float inv = rsqrtf(1.0f + 1e-5f);
        float s = g[tid] * inv;
        sc1[tid] = s;
        ep1[tid] = b1[tid] * s + be[tid];
        ep2[tid] = b2[tid];
    }
    {   // stage: At[node][k] = h[self] + sum_neighbors h[s]  (gather fused)
        int r = tid >> 4, q = tid & 15;
        #pragma unroll
        for (int p = 0; p < 4; ++p) {
            int rr = p * 16 + r;
            int n = n0 + rr;
            float4 a0 = make_float4(0.f, 0.f, 0.f, 0.f);
            if (n < N_NODES) {
                a0 = h4[n * 16 + q];                      // self term
                int deg = min(cnt[n], CAP);
                const int4* al4 = (const int4*)(adj + n * CAP);
                float4 a1 = make_float4(0.f, 0.f, 0.f, 0.f);
                float4 a2 = a1, a3 = a1, a4 = a1, a5 = a1, a6 = a1, a7 = a1;
                int g8 = (deg + 7) >> 3;
                for (int i = 0; i < g8; ++i) {
                    int4 sa = al4[2 * i];
                    int4 sb = al4[2 * i + 1];
                    int base = i * 8;       // mask tail -> sentinel zero row
                    int s0 = (base + 0 < deg) ? sa.x : N_NODES;
                    int s1 = (base + 1 < deg) ? sa.y : N_NODES;
                    int s2 = (base + 2 < deg) ? sa.z : N_NODES;
                    int s3 = (base + 3 < deg) ? sa.w : N_NODES;
                    int s4 = (base + 4 < deg) ? sb.x : N_NODES;
                    int s5 = (base + 5 < deg) ? sb.y : N_NODES;
                    int s6 = (base + 6 < deg) ? sb.z : N_NODES;
                    int s7 = (base + 7 < deg) ? sb.w : N_NODES;
                    float4 v0 = h4[s0 * 16 + q];
                    float4 v1 = h4[s1 * 16 + q];
                    float4 v2 = h4[s2 * 16 + q];
                    float4 v3 = h4[s3 * 16 + q];
                    float4 v4 = h4[s4 * 16 + q];
                    float4 v5 = h4[s5 * 16 + q];
                    float4 v6 = h4[s6 * 16 + q];
                    float4 v7 = h4[s7 * 16 + q];
                    f4add(a0, v0); f4add(a1, v1); f4add(a2, v2); f4add(a3, v3);
                    f4add(a4, v4); f4add(a5, v5); f4add(a6, v6); f4add(a7, v7);
                }
                f4add(a0, a1); f4add(a2, a3); f4add(a4, a5); f4add(a6, a7);
                f4add(a0, a2); f4add(a4, a6); f4add(a0, a4);
            }
            *(float4*)(At + rr * AP + q * 4) = a0;   // lane-consecutive, no conflict
        }
    }
    __syncthreads();

    int tr = tid >> 4, tc = tid & 15;
    float acc[4][4];
    #pragma unroll
    for (int e = 0; e < 4; ++e)
        #pragma unroll
        for (int j = 0; j < 4; ++j) acc[e][j] = 0.f;

    mm64(At, Wbuf, acc, tr, tc);
    __syncthreads();                   // all waves done reading At and Wbuf(W1)
    // epilogue 1 (y into At) + stage W2 into Wbuf, then one barrier
    #pragma unroll
    for (int e = 0; e < 4; ++e) {
        float4 o;
        o.x = elu(acc[e][0] * sc1[tc * 4 + 0] + ep1[tc * 4 + 0]);
        o.y = elu(acc[e][1] * sc1[tc * 4 + 1] + ep1[tc * 4 + 1]);
        o.z = elu(acc[e][2] * sc1[tc * 4 + 2] + ep1[tc * 4 + 2]);
        o.w = elu(acc[e][3] * sc1[tc * 4 + 3] + ep1[tc * 4 + 3]);
        *(float4*)(At + (tr * 4 + e) * AP + tc * 4) = o;   // lane-consecutive
    }
    for (int idx = tid; idx < 1024; idx += 256)
        ((float4*)Wbuf)[idx] = ((const float4*)W2)[idx];
    __syncthreads();
    #pragma unroll
    for (int e = 0; e < 4; ++e)
        #pragma unroll
        for (int j = 0; j < 4; ++j) acc[e][j] = 0.f;

    mm64(At, Wbuf, acc, tr, tc);
    #pragma unroll
    for (int e = 0; e < 4; ++e) {      // epilogue 2: +b2, outer elu, store
        int n = n0 + tr * 4 + e;
        if (n < N_NODES) {
            float4 o;
            o.x = elu(acc[e][0] + ep2[tc * 4 + 0]);
            o.y = elu(acc[e][1] + ep2[tc * 4 + 1]);
            o.z = elu(acc[e][2] + ep2[tc * 4 + 2]);
            o.w = elu(acc[e][3] + ep2[tc * 4 + 3]);
            ((float4*)hout)[n * 16 + tc] = o;
        }
    }
}

// ---------------- mean pool per graph (batch sorted -> binary search bounds) ----
__global__ void pool_k(const float4* __restrict__ h, const int* __restrict__ batch,
                       float4* __restrict__ pooled) {
    int gph = blockIdx.x;
    int tid = threadIdx.x;          // 256
    int lo = 0, hi = N_NODES;
    while (lo < hi) { int mid = (lo + hi) >> 1; if (batch[mid] < gph) lo = mid + 1; else hi = mid; }
    int start = lo;
    hi = N_NODES;
    while (lo < hi) { int mid = (lo + hi) >> 1; if (batch[mid] < gph + 1) lo = mid + 1; else hi = mid; }
    int end = lo;
    int q = tid & 15, r = tid >> 4;
    float4 acc = make_float4(0.f, 0.f, 0.f, 0.f);
    for (int n = start + r; n < end; n += 16) {
        float4 v = h[n * 16 + q];
        acc.x += v.x; acc.y += v.y; acc.z += v.z; acc.w += v.w;
    }
    __shared__ float4 red[256];
    red[tid] = acc;
    __syncthreads();
    for (int s = 8; s > 0; s >>= 1) {
        if (r < s) {
            float4 o = red[(r + s) * 16 + q];
            float4 m = red[r * 16 + q];
            m.x += o.x; m.y += o.y; m.z += o.z; m.w += o.w;
            red[r * 16 + q] = m;
        }
        __syncthreads();
    }
    if (r == 0) {
        float invc = 1.0f / fmaxf((float)(end - start), 1.0f);
        float4 m = red[q];
        m.x *= invc; m.y *= invc; m.z *= invc; m.w *= invc;
        pooled[gph * 16 + q] = m;
    }
}

// ---------------- readout head: one wave per graph, lane j owns output j ------
__global__ void __launch_bounds__(256) head_k(const float* __restrict__ pooled,
    const float* __restrict__ Wr1, const float* __restrict__ br1,
    const float* __restrict__ Wr2, const float* __restrict__ br2,
    const float* __restrict__ Wo,  const float* __restrict__ bo,
    float* __restrict__ out) {
    __shared__ float ylds[4][64];
    int wid = threadIdx.x >> 6, j = threadIdx.x & 63;
    int gph = blockIdx.x * 4 + wid;   // 32 blocks x 4 waves = 128 graphs
    float acc = 0.f;
    #pragma unroll 8
    for (int k = 0; k < 64; ++k)
        acc += pooled[gph * 64 + k] * Wr1[k * 64 + j];   // bcast * coalesced
    float yv = acc + br1[j];
    ylds[wid][j] = elu(yv);
    __syncthreads();
    float acc2 = 0.f;
    #pragma unroll 8
    for (int k = 0; k < 64; ++k)
        acc2 += ylds[wid][k] * Wr2[k * 64 + j];
    float p = (acc2 + br2[j]) * Wo[j];
    #pragma unroll
    for (int off = 32; off > 0; off >>= 1) p += __shfl_down(p, off);
    if (j == 0) out[gph] = bo[0] + p;
}

extern "C" void kernel_launch(void* const* d_in, const int* in_sizes, int n_in,
                              void* d_out, int out_size, void* d_ws, size_t ws_size,
                              hipStream_t stream) {
    const int*   x     = (const int*)d_in[0];
    const int*   ei    = (const int*)d_in[1];
    const int*   batch = (const int*)d_in[2];
    const float* emb   = (const float*)d_in[3];
    const float* P[24];
    for (int i = 0; i < 24; ++i) P[i] = (const float*)d_in[4 + i];

    char* ws = (char*)d_ws;
    float* hA     = (float*)(ws + 0);           // (N+1) rows x 256B
    float* hB     = (float*)(ws + 26000000);    // (N+1) rows x 256B
    int*   adj    = (int*)  (ws + 52000000);    // 25.6 MB (N*CAP)
    int*   cnt    = (int*)  (ws + 78000000);    // 0.4 MB
    float* pooled = (float*)(ws + 78400000);    // 32 KB

    hipMemsetAsync(cnt, 0, N_NODES * sizeof(int), stream);
    hipMemsetAsync(hA + N_NODES * 64, 0, 64 * sizeof(float), stream);  // sentinels
    hipMemsetAsync(hB + N_NODES * 64, 0, 64 * sizeof(float), stream);
    scatter_k<<<8 * ((N_EDGES + 255) / 256), 256, 0, stream>>>(ei, cnt, adj);
    embed_k<<<(N_NODES * 16 + 255) / 256, 256, 0, stream>>>(x, (const float4*)emb, (float4*)hA);
    // ping-pong: L0 hA->hB, L1 hB->hA, L2 hA->hB
    for (int L = 0; L < 3; ++L) {
        const float* const* p = P + 6 * L;
        const float* hin = (L & 1) ? hB : hA;
        float* hout      = (L & 1) ? hA : hB;
        mlp_k<<<(N_NODES + 63) / 64, 256, 0, stream>>>(
            hin, hout, adj, cnt, p[0], p[1], p[2], p[3], p[4], p[5]);
    }
    pool_k<<<G_GRAPHS, 256, 0, stream>>>((const float4*)hB, batch, (float4*)pooled);
    head_k<<<32, 256, 0, stream>>>(pooled, P[18], P[19], P[20], P[21], P[22], P[23],
                                   (float*)d_out);
}

// Round 15
// 371.288 us; speedup vs baseline: 2.4126x; 1.1291x over previous
//
#include <hip/hip_runtime.h>
#include <hip/hip_bf16.h>

#define N_NODES 100000
#define N_EDGES 1200000
#define G_GRAPHS 128
#define CAP 64      // max in-degree capacity (Poisson mean 12; max deg @1e-10 ~ 40)
#define AP 68       // A row stride (floats): 272B = 17*16B, keeps b128 aligned
#define SLICE_N 12500   // N_NODES / 8 XCDs

// bf16 helpers: RTN pack, shift/mask unpack (hi element needs only a mask)
__device__ __forceinline__ ushort f2bf(float f) {
    uint u = __float_as_uint(f);
    return (ushort)((u + 0x7FFF + ((u >> 16) & 1)) >> 16);
}
__device__ __forceinline__ uint pack2(float a, float b) {
    return (uint)f2bf(a) | ((uint)f2bf(b) << 16);
}
// unpack uint2 (4 bf16) -> float4
__device__ __forceinline__ float4 bf4(uint2 w) {
    float4 r;
    r.x = __uint_as_float(w.x << 16);
    r.y = __uint_as_float(w.x & 0xFFFF0000u);
    r.z = __uint_as_float(w.y << 16);
    r.w = __uint_as_float(w.y & 0xFFFF0000u);
    return r;
}

// ---------------- CSR build (by dst), XCD-sliced (R11: 72->57MB writes) ------
__global__ void scatter_k(const int* __restrict__ ei, int* __restrict__ cnt,
                          int* __restrict__ adj) {
    int slice = blockIdx.x & 7;
    int e = (blockIdx.x >> 3) * 256 + threadIdx.x;
    if (e >= N_EDGES) return;
    int s = ei[e];             // src
    int d = ei[N_EDGES + e];   // dst
    s = min(max(s, 0), N_NODES - 1);
    d = min(max(d, 0), N_NODES - 1);
    if (d / SLICE_N != slice) return;    // another XCD's dst range
    int pos = atomicAdd(&cnt[d], 1);
    if (pos < CAP) adj[d * CAP + pos] = s;
}

// ---------------- embedding gather -> bf16 h; also zero cnt + sentinels ------
__global__ void embed_k(const int* __restrict__ x, const float4* __restrict__ emb,
                        ushort* __restrict__ hbfA, ushort* __restrict__ hbfB,
                        int* __restrict__ cnt) {
    int t = blockIdx.x * 256 + threadIdx.x;
    if (t > N_NODES * 16 + 15) return;
    int n = t >> 4, q = t & 15;
    if (t < N_NODES) cnt[t] = 0;                    // fold memset
    if (n < N_NODES) {
        float4 v = emb[x[n] * 16 + q];
        *(uint2*)(hbfA + n * 64 + q * 4) = make_uint2(pack2(v.x, v.y), pack2(v.z, v.w));
    } else {                                        // sentinel rows = 0
        *(uint2*)(hbfA + n * 64 + q * 4) = make_uint2(0u, 0u);
        *(uint2*)(hbfB + n * 64 + q * 4) = make_uint2(0u, 0u);
    }
}

__device__ __forceinline__ void f4add(float4& a, const float4 b) {
    a.x += b.x; a.y += b.y; a.z += b.z; a.w += b.w;
}

__device__ __forceinline__ float elu(float v) { return v > 0.f ? v : expm1f(v); }

// 64x64x64 micro-tiled matmul, A row-major [node][k] stride AP (conflict-free).
// R12 lesson: one wv live at a time, unroll 2 -> ~45 VGPR live set.
#define FMA16(comp, wv)                                                        \
    acc[0][0] += av0.comp * wv.x; acc[0][1] += av0.comp * wv.y;                \
    acc[0][2] += av0.comp * wv.z; acc[0][3] += av0.comp * wv.w;                \
    acc[1][0] += av1.comp * wv.x; acc[1][1] += av1.comp * wv.y;                \
    acc[1][2] += av1.comp * wv.z; acc[1][3] += av1.comp * wv.w;                \
    acc[2][0] += av2.comp * wv.x; acc[2][1] += av2.comp * wv.y;                \
    acc[2][2] += av2.comp * wv.z; acc[2][3] += av2.comp * wv.w;                \
    acc[3][0] += av3.comp * wv.x; acc[3][1] += av3.comp * wv.y;                \
    acc[3][2] += av3.comp * wv.z; acc[3][3] += av3.comp * wv.w;

__device__ __forceinline__ void mm64(const float* __restrict__ A,
                                     const float* __restrict__ Ws,
                                     float acc[4][4], int tr, int tc) {
    #pragma unroll 2
    for (int k4 = 0; k4 < 16; ++k4) {
        float4 av0 = *(const float4*)(A + (tr * 4 + 0) * AP + k4 * 4);
        float4 av1 = *(const float4*)(A + (tr * 4 + 1) * AP + k4 * 4);
        float4 av2 = *(const float4*)(A + (tr * 4 + 2) * AP + k4 * 4);
        float4 av3 = *(const float4*)(A + (tr * 4 + 3) * AP + k4 * 4);
        {
            float4 wv = *(const float4*)(Ws + (k4 * 4 + 0) * 64 + tc * 4);
            FMA16(x, wv)
        }
        {
            float4 wv = *(const float4*)(Ws + (k4 * 4 + 1) * 64 + tc * 4);
            FMA16(y, wv)
        }
        {
            float4 wv = *(const float4*)(Ws + (k4 * 4 + 2) * 64 + tc * 4);
            FMA16(z, wv)
        }
        {
            float4 wv = *(const float4*)(Ws + (k4 * 4 + 3) * 64 + tc * 4);
            FMA16(w, wv)
        }
    }
}

// ------ fused GIN layer: hout <- elu(W2^T(elu(BN(W1^T(self+neigh)))) + b2) ----
// h stored bf16 (128B/row): halves the gather traffic that bounds this kernel
// (R14: FETCH 147MB @ 2.35TB/s = 63us of 75us). fp32 accumulate + fp32 GEMM;
// mean-pool over ~780 nodes/graph shrinks quantization noise ~28x at readout.
__global__ void __launch_bounds__(256, 4) mlp_k(const ushort* __restrict__ hin,
    ushort* __restrict__ hout, const int* __restrict__ adj,
    const int* __restrict__ cnt,
    const float* __restrict__ W1, const float* __restrict__ b1,
    const float* __restrict__ g,  const float* __restrict__ be,
    const float* __restrict__ W2, const float* __restrict__ b2) {
    __shared__ float At[64 * AP];     // A row-major [node][k]; reused for y
    __shared__ float Wbuf[4096];      // W1 for mm1, then W2 for mm2
    __shared__ float sc1[64], ep1[64], ep2[64];
    int tid = threadIdx.x;
    int n0 = blockIdx.x * 64;

    for (int idx = tid; idx < 1024; idx += 256)
        ((float4*)Wbuf)[idx] = ((const float4*)W1)[idx];
    if (tid < 64) {
        const float inv = rsqrtf(1.0f + 1e-5f);
        float s = g[tid] * inv;
        sc1[tid] = s;
        ep1[tid] = b1[tid] * s + be[tid];
        ep2[tid] = b2[tid];
    }
    {   // stage: At[node][k] = h[self] + sum_neighbors h[s]  (bf16 gather, fp32 acc)
        int r = tid >> 4, q = tid & 15;
        #pragma unroll
        for (int p = 0; p < 4; ++p) {
            int rr = p * 16 + r;
            int n = n0 + rr;
            float4 a0 = make_float4(0.f, 0.f, 0.f, 0.f);
            if (n < N_NODES) {
                a0 = bf4(*(const uint2*)(hin + n * 64 + q * 4));   // self
                int deg = min(cnt[n], CAP);
                const int4* al4 = (const int4*)(adj + n * CAP);
                float4 a1 = make_float4(0.f, 0.f, 0.f, 0.f);
                float4 a2 = a1, a3 = a1, a4 = a1, a5 = a1, a6 = a1, a7 = a1;
                int g8 = (deg + 7) >> 3;
                for (int i = 0; i < g8; ++i) {
                    int4 sa = al4[2 * i];
                    int4 sb = al4[2 * i + 1];
                    int base = i * 8;       // mask tail -> sentinel zero row
                    int s0 = (base + 0 < deg) ? sa.x : N_NODES;
                    int s1 = (base + 1 < deg) ? sa.y : N_NODES;
                    int s2 = (base + 2 < deg) ? sa.z : N_NODES;
                    int s3 = (base + 3 < deg) ? sa.w : N_NODES;
                    int s4 = (base + 4 < deg) ? sb.x : N_NODES;
                    int s5 = (base + 5 < deg) ? sb.y : N_NODES;
                    int s6 = (base + 6 < deg) ? sb.z : N_NODES;
                    int s7 = (base + 7 < deg) ? sb.w : N_NODES;
                    uint2 w0 = *(const uint2*)(hin + s0 * 64 + q * 4);
                    uint2 w1 = *(const uint2*)(hin + s1 * 64 + q * 4);
                    uint2 w2 = *(const uint2*)(hin + s2 * 64 + q * 4);
                    uint2 w3 = *(const uint2*)(hin + s3 * 64 + q * 4);
                    uint2 w4 = *(const uint2*)(hin + s4 * 64 + q * 4);
                    uint2 w5 = *(const uint2*)(hin + s5 * 64 + q * 4);
                    uint2 w6 = *(const uint2*)(hin + s6 * 64 + q * 4);
                    uint2 w7 = *(const uint2*)(hin + s7 * 64 + q * 4);
                    f4add(a0, bf4(w0)); f4add(a1, bf4(w1));
                    f4add(a2, bf4(w2)); f4add(a3, bf4(w3));
                    f4add(a4, bf4(w4)); f4add(a5, bf4(w5));
                    f4add(a6, bf4(w6)); f4add(a7, bf4(w7));
                }
                f4add(a0, a1); f4add(a2, a3); f4add(a4, a5); f4add(a6, a7);
                f4add(a0, a2); f4add(a4, a6); f4add(a0, a4);
            }
            *(float4*)(At + rr * AP + q * 4) = a0;   // lane-consecutive, no conflict
        }
    }
    __syncthreads();

    int tr = tid >> 4, tc = tid & 15;
    float acc[4][4];
    #pragma unroll
    for (int e = 0; e < 4; ++e)
        #pragma unroll
        for (int j = 0; j < 4; ++j) acc[e][j] = 0.f;

    mm64(At, Wbuf, acc, tr, tc);
    __syncthreads();                   // all waves done reading At and Wbuf(W1)
    // epilogue 1 (y into At) + stage W2 into Wbuf, then one barrier
    #pragma unroll
    for (int e = 0; e < 4; ++e) {
        float4 o;
        o.x = elu(acc[e][0] * sc1[tc * 4 + 0] + ep1[tc * 4 + 0]);
        o.y = elu(acc[e][1] * sc1[tc * 4 + 1] + ep1[tc * 4 + 1]);
        o.z = elu(acc[e][2] * sc1[tc * 4 + 2] + ep1[tc * 4 + 2]);
        o.w = elu(acc[e][3] * sc1[tc * 4 + 3] + ep1[tc * 4 + 3]);
        *(float4*)(At + (tr * 4 + e) * AP + tc * 4) = o;   // lane-consecutive
    }
    for (int idx = tid; idx < 1024; idx += 256)
        ((float4*)Wbuf)[idx] = ((const float4*)W2)[idx];
    __syncthreads();
    #pragma unroll
    for (int e = 0; e < 4; ++e)
        #pragma unroll
        for (int j = 0; j < 4; ++j) acc[e][j] = 0.f;

    mm64(At, Wbuf, acc, tr, tc);
    #pragma unroll
    for (int e = 0; e < 4; ++e) {      // epilogue 2: +b2, outer elu, bf16 store
        int n = n0 + tr * 4 + e;
        if (n < N_NODES) {
            float o0 = elu(acc[e][0] + ep2[tc * 4 + 0]);
            float o1 = elu(acc[e][1] + ep2[tc * 4 + 1]);
            float o2 = elu(acc[e][2] + ep2[tc * 4 + 2]);
            float o3 = elu(acc[e][3] + ep2[tc * 4 + 3]);
            *(uint2*)(hout + n * 64 + tc * 4) = make_uint2(pack2(o0, o1), pack2(o2, o3));
        }
    }
}

// ---------------- mean pool per graph (batch sorted -> binary search bounds) ----
__global__ void pool_k(const ushort* __restrict__ h, const int* __restrict__ batch,
                       float4* __restrict__ pooled) {
    int gph = blockIdx.x;
    int tid = threadIdx.x;          // 256
    int lo = 0, hi = N_NODES;
    while (lo < hi) { int mid = (lo + hi) >> 1; if (batch[mid] < gph) lo = mid + 1; else hi = mid; }
    int start = lo;
    hi = N_NODES;
    while (lo < hi) { int mid = (lo + hi) >> 1; if (batch[mid] < gph + 1) lo = mid + 1; else hi = mid; }
    int end = lo;
    int q = tid & 15, r = tid >> 4;
    float4 acc = make_float4(0.f, 0.f, 0.f, 0.f);
    for (int n = start + r; n < end; n += 16)
        f4add(acc, bf4(*(const uint2*)(h + n * 64 + q * 4)));
    __shared__ float4 red[256];
    red[tid] = acc;
    __syncthreads();
    for (int s = 8; s > 0; s >>= 1) {
        if (r < s) {
            float4 o = red[(r + s) * 16 + q];
            float4 m = red[r * 16 + q];
            m.x += o.x; m.y += o.y; m.z += o.z; m.w += o.w;
            red[r * 16 + q] = m;
        }
        __syncthreads();
    }
    if (r == 0) {
        float invc = 1.0f / fmaxf((float)(end - start), 1.0f);
        float4 m = red[q];
        m.x *= invc; m.y *= invc; m.z *= invc; m.w *= invc;
        pooled[gph * 16 + q] = m;
    }
}

// ---------------- readout head: one wave per graph, lane j owns output j ------
__global__ void __launch_bounds__(256) head_k(const float* __restrict__ pooled,
    const float* __restrict__ Wr1, const float* __restrict__ br1,
    const float* __restrict__ Wr2, const float* __restrict__ br2,
    const float* __restrict__ Wo,  const float* __restrict__ bo,
    float* __restrict__ out) {
    __shared__ float ylds[4][64];
    int wid = threadIdx.x >> 6, j = threadIdx.x & 63;
    int gph = blockIdx.x * 4 + wid;   // 32 blocks x 4 waves = 128 graphs
    float acc = 0.f;
    #pragma unroll 8
    for (int k = 0; k < 64; ++k)
        acc += pooled[gph * 64 + k] * Wr1[k * 64 + j];   // bcast * coalesced
    float yv = acc + br1[j];
    ylds[wid][j] = elu(yv);
    __syncthreads();
    float acc2 = 0.f;
    #pragma unroll 8
    for (int k = 0; k < 64; ++k)
        acc2 += ylds[wid][k] * Wr2[k * 64 + j];
    float p = (acc2 + br2[j]) * Wo[j];
    #pragma unroll
    for (int off = 32; off > 0; off >>= 1) p += __shfl_down(p, off);
    if (j == 0) out[gph] = bo[0] + p;
}

extern "C" void kernel_launch(void* const* d_in, const int* in_sizes, int n_in,
                              void* d_out, int out_size, void* d_ws, size_t ws_size,
                              hipStream_t stream) {
    const int*   x     = (const int*)d_in[0];
    const int*   ei    = (const int*)d_in[1];
    const int*   batch = (const int*)d_in[2];
    const float* emb   = (const float*)d_in[3];
    const float* P[24];
    for (int i = 0; i < 24; ++i) P[i] = (const float*)d_in[4 + i];

    char* ws = (char*)d_ws;
    ushort* hbfA  = (ushort*)(ws + 0);          // (N+1)*64 bf16 = 12.81 MB
    ushort* hbfB  = (ushort*)(ws + 13000000);   // 12.81 MB
    int*    adj   = (int*)   (ws + 26000000);   // 25.6 MB (N*CAP)
    int*    cnt   = (int*)   (ws + 52000000);   // 0.4 MB
    float*  pooled= (float*) (ws + 52500000);   // 32 KB

    // embed first: zeroes cnt + both sentinel rows (no memsets, fewer dispatches)
    embed_k<<<(N_NODES * 16 + 16 + 255) / 256, 256, 0, stream>>>(
        x, (const float4*)emb, hbfA, hbfB, cnt);
    scatter_k<<<8 * ((N_EDGES + 255) / 256), 256, 0, stream>>>(ei, cnt, adj);
    // ping-pong: L0 hbfA->hbfB, L1 hbfB->hbfA, L2 hbfA->hbfB
    for (int L = 0; L < 3; ++L) {
        const float* const* p = P + 6 * L;
        const ushort* hin = (L & 1) ? hbfB : hbfA;
        ushort* hout      = (L & 1) ? hbfA : hbfB;
        mlp_k<<<(N_NODES + 63) / 64, 256, 0, stream>>>(
            hin, hout, adj, cnt, p[0], p[1], p[2], p[3], p[4], p[5]);
    }
    pool_k<<<G_GRAPHS, 256, 0, stream>>>(hbfB, batch, (float4*)pooled);
    head_k<<<32, 256, 0, stream>>>(pooled, P[18], P[19], P[20], P[21], P[22], P[23],
                                   (float*)d_out);
}